// Round 6
// baseline (172.710 us; speedup 1.0000x reference)
//
#include <hip/hip_runtime.h>
#include <hip/hip_bf16.h>
#include <stdint.h>

// SelfAttention: x[4,2048,1024] fp32; q=xWq+bq, k=xWk+bk, v=xWv+bv;
// out = softmax(q k^T / 32) v.
// R6: BK=32, 3x24KiB LDS rotation -> 72 KiB/block -> 2 blocks/CU (16 waves/CU),
// restoring inter-block overlap (m114 mechanism). Counted vmcnt(3), stage-issue-
// early, 2-bit XOR swizzle (parity-mixing), setprio. One barrier per K-tile.

typedef short bf16x8 __attribute__((ext_vector_type(8)));
typedef float f32x4 __attribute__((ext_vector_type(4)));
typedef unsigned short us4 __attribute__((ext_vector_type(4)));
typedef _Float16 h4 __attribute__((ext_vector_type(4)));
typedef unsigned short us;

#define B_ 4
#define S_ 2048
#define D_ 1024

__device__ __forceinline__ us f2bf(float f) {
  unsigned int u = __float_as_uint(f);
  unsigned int r = (u + 0x7fffu + ((u >> 16) & 1u)) >> 16;  // RNE
  return (us)r;
}

// async global->LDS, 16B per lane. lds addr wave-uniform; global per-lane.
__device__ __forceinline__ void gl2lds16(void* lds, const void* g) {
  __builtin_amdgcn_global_load_lds(
      (const __attribute__((address_space(1))) unsigned int*)(uintptr_t)g,
      (__attribute__((address_space(3))) unsigned int*)(uintptr_t)lds,
      16, 0, 0);
}

__device__ __forceinline__ void wait_vm3() {
  asm volatile("s_waitcnt vmcnt(3)" ::: "memory");
}
__device__ __forceinline__ void wait_vm0() {
  asm volatile("s_waitcnt vmcnt(0)" ::: "memory");
}
__device__ __forceinline__ void sbar() {
  __builtin_amdgcn_sched_barrier(0);
  __builtin_amdgcn_s_barrier();
  __builtin_amdgcn_sched_barrier(0);
}

// Stage one BK=32 K-tile: (BM+BN) rows x 64B, 3 rounds of 128 rows,
// 1 gl2lds per thread per round. LDS dest linear; global source carries the
// inverse swizzle: LDS[row][slot] = G[row][slot ^ g(row)],
// g(row) = (row&3) ^ ((row>>2)&3)  (lane-only: g = ((l>>2)&3)^((l>>4)&3)).
template<int BM>
__device__ __forceinline__ void stage3(us* buf, const us* gA, size_t sA,
                                       const us* gB, size_t sB, int wave, int lane) {
  int slot = (((lane & 3) ^ ((lane >> 2) & 3) ^ ((lane >> 4) & 3)) << 4);
  char* l = (char*)buf;
#pragma unroll
  for (int r = 0; r < 3; ++r) {
    int row = r * 128 + wave * 16 + (lane >> 2);
    const char* src = (r * 128 < BM)
        ? (const char*)gA + (size_t)row * sA + slot
        : (const char*)gB + (size_t)(row - BM) * sB + slot;
    gl2lds16(l + r * 8192 + wave * 1024, src);
  }
}

// EPI: 0 = qkv (bf16 out + bias, 3 mats folded in N), 1 = s2 (fp16, *1/32), 2 = s3 (f32)
template<int EPI, int BM, int BN, int WNS>
__global__ __launch_bounds__(512, 4) void gemm32(
    const us* __restrict__ Aall, const us* __restrict__ Ball,
    size_t aBatch, size_t bBatch, int sAe, int sBe, int nt,
    const float* __restrict__ bq, const float* __restrict__ bk,
    const float* __restrict__ bv, void* __restrict__ outp) {
  __shared__ __align__(16) us lds3[3][(BM + BN) * 32];   // 3 x 24 KiB
  int tid = threadIdx.x, lane = tid & 63, wave = tid >> 6;
  int wm = wave / WNS, wn = wave % WNS;
  int m0 = blockIdx.x * BM, n0 = blockIdx.y * BN;
  size_t bz = blockIdx.z;
  const us* gA = Aall + bz * aBatch + (size_t)m0 * sAe;
  const us* gB = Ball + bz * bBatch + (size_t)n0 * sBe;
  size_t sA = (size_t)sAe * 2, sB = (size_t)sBe * 2;

  // prologue: tiles 0,1 staged (3 loads each)
  stage3<BM>(lds3[0], gA, sA, gB, sB, wave, lane);
  stage3<BM>(lds3[1], gA + 32, sA, gB + 32, sB, wave, lane);

  int r15 = lane & 15, kg = lane >> 4;
  int x0 = ((kg ^ (r15 & 3) ^ ((r15 >> 2) & 3)) << 4);  // swizzled k-slot byte
  f32x4 acc[4][4] = {};

  for (int t = 0; t < nt; ++t) {
    if (t == nt - 1) wait_vm0(); else wait_vm3();
    sbar();   // tile-t staging drained by every wave; prior reads complete
    const us* buf = lds3[t % 3];
    if (t + 2 < nt)
      stage3<BM>(lds3[(t + 2) % 3], gA + (size_t)(t + 2) * 32, sA,
                 gB + (size_t)(t + 2) * 32, sB, wave, lane);
    const char* pa = (const char*)buf + (size_t)(wm * 64 + r15) * 64;
    const char* pb = (const char*)buf + (size_t)(BM + wn * 64 + r15) * 64;
    bf16x8 Af[4], Bf[4];
#pragma unroll
    for (int f = 0; f < 4; ++f) Af[f] = *(const bf16x8*)(pa + f * 1024 + x0);
#pragma unroll
    for (int f = 0; f < 4; ++f) Bf[f] = *(const bf16x8*)(pb + f * 1024 + x0);
    __builtin_amdgcn_s_setprio(1);
#pragma unroll
    for (int fn = 0; fn < 4; ++fn)
#pragma unroll
      for (int fm = 0; fm < 4; ++fm)
        acc[fm][fn] = __builtin_amdgcn_mfma_f32_16x16x32_bf16(Af[fm], Bf[fn], acc[fm][fn], 0, 0, 0);
    __builtin_amdgcn_s_setprio(0);
  }

#pragma unroll
  for (int fm = 0; fm < 4; ++fm)
#pragma unroll
    for (int fn = 0; fn < 4; ++fn) {
      int col = n0 + wn * 64 + fn * 16 + r15;
      int row0 = m0 + wm * 64 + fm * 16 + ((lane >> 4) << 2);
      if constexpr (EPI == 0) {
        int mat = col >> 10;
        const float* bp = (mat == 0) ? bq : (mat == 1) ? bk : bv;
        float bb = bp[col & 1023];
        us* ob = (us*)outp + ((size_t)mat << 23);
#pragma unroll
        for (int r = 0; r < 4; ++r)
          ob[(size_t)(row0 + r) * D_ + (col & 1023)] = f2bf(acc[fm][fn][r] + bb);
      } else if constexpr (EPI == 1) {
        _Float16* sc = (_Float16*)outp + bz * (size_t)(S_ * S_);
#pragma unroll
        for (int r = 0; r < 4; ++r)
          sc[(size_t)(row0 + r) * S_ + col] = (_Float16)(acc[fm][fn][r] * 0.03125f);
      } else {
        float* ob = (float*)outp + bz * (size_t)(S_ * D_);
#pragma unroll
        for (int r = 0; r < 4; ++r)
          ob[(size_t)(row0 + r) * D_ + col] = acc[fm][fn][r];
      }
    }
}

// ---------------- W [k][n] fp32 -> Wt bf16 [n][k] (n = mat*1024 + col) ----------------
__global__ __launch_bounds__(256) void wt_prep(const float* __restrict__ Wq,
                                               const float* __restrict__ Wk,
                                               const float* __restrict__ Wv,
                                               us* __restrict__ wtb) {
  __shared__ us hs[64][65];
  int mat = blockIdx.z;
  const float* W = (mat == 0) ? Wq : (mat == 1) ? Wk : Wv;
  int n0 = blockIdx.x * 64, k0 = blockIdx.y * 64;
  int tid = threadIdx.x;
#pragma unroll
  for (int i = 0; i < 16; ++i) {
    int idx = tid + i * 256;
    int r = idx >> 6, c = idx & 63;  // r: k, c: n
    hs[r][c] = f2bf(W[(size_t)(k0 + r) * D_ + (n0 + c)]);
  }
  __syncthreads();
  us* o = wtb + ((size_t)mat << 20);
#pragma unroll
  for (int i = 0; i < 16; ++i) {
    int idx = tid + i * 256;
    int r = idx >> 6, c = idx & 63;  // r: n, c: k
    o[(size_t)(n0 + r) * D_ + (k0 + c)] = hs[c][r];
  }
}

// ---------------- x fp32 -> xb bf16 (same [m][k] layout) ----------------
__global__ __launch_bounds__(256) void xcast(const float* __restrict__ x,
                                             us* __restrict__ xb) {
  size_t i = ((size_t)blockIdx.x * 256 + threadIdx.x) * 8;
  float4 f0 = *(const float4*)(x + i);
  float4 f1 = *(const float4*)(x + i + 4);
  float vals[8] = {f0.x, f0.y, f0.z, f0.w, f1.x, f1.y, f1.z, f1.w};
  union { bf16x8 v; us s_[8]; } H;
#pragma unroll
  for (int e = 0; e < 8; ++e) H.s_[e] = f2bf(vals[e]);
  *(bf16x8*)(xb + i) = H.v;
}

// ---------------- v [b][t][d] -> vT [b][d][t] ----------------
__global__ __launch_bounds__(256) void vtrans(const us* __restrict__ vin,
                                              us* __restrict__ vout) {
  int b = blockIdx.z;
  const us* vi = vin + (size_t)b * S_ * D_;
  us* vo = vout + (size_t)b * D_ * S_;
  int d0 = blockIdx.x * 64, t0 = blockIdx.y * 64;
  __shared__ us ts[64][72];
  int tid = threadIdx.x;
#pragma unroll
  for (int i = 0; i < 16; ++i) {
    int idx = tid + i * 256;
    int r = idx >> 6, c = idx & 63;  // r: t, c: d
    ts[r][c] = vi[(size_t)(t0 + r) * D_ + d0 + c];
  }
  __syncthreads();
#pragma unroll
  for (int i = 0; i < 16; ++i) {
    int idx = tid + i * 256;
    int r = idx >> 6, c = idx & 63;  // r: d, c: t
    vo[(size_t)(d0 + r) * S_ + t0 + c] = ts[c][r];
  }
}

// ---------------- row softmax: fp16 scores -> P bf16 ----------------
__global__ __launch_bounds__(256) void softmax_k(const _Float16* __restrict__ scores,
                                                 us* __restrict__ pb) {
  int row = blockIdx.x, tid = threadIdx.x, lane = tid & 63, wave = tid >> 6;
  const _Float16* s = scores + (size_t)row * S_;
  h4 a4 = ((const h4*)s)[tid];
  h4 b4 = ((const h4*)s)[256 + tid];
  float a[8] = {(float)a4.x, (float)a4.y, (float)a4.z, (float)a4.w,
                (float)b4.x, (float)b4.y, (float)b4.z, (float)b4.w};
  float m = a[0];
#pragma unroll
  for (int e = 1; e < 8; ++e) m = fmaxf(m, a[e]);
#pragma unroll
  for (int o = 32; o; o >>= 1) m = fmaxf(m, __shfl_xor(m, o));
  __shared__ float red[4];
  if (lane == 0) red[wave] = m;
  __syncthreads();
  m = fmaxf(fmaxf(red[0], red[1]), fmaxf(red[2], red[3]));
  float p[8];
  float sum = 0.f;
#pragma unroll
  for (int e = 0; e < 8; ++e) { p[e] = expf(a[e] - m); sum += p[e]; }
#pragma unroll
  for (int o = 32; o; o >>= 1) sum += __shfl_xor(sum, o);
  __syncthreads();  // all reads of red done before reuse
  if (lane == 0) red[wave] = sum;
  __syncthreads();
  float inv = 1.0f / (red[0] + red[1] + red[2] + red[3]);
  us h[8];
#pragma unroll
  for (int e = 0; e < 8; ++e) h[e] = f2bf(p[e] * inv);
  size_t base = (size_t)row * S_;
  *(us4*)(pb + base + tid * 4) = (us4){h[0], h[1], h[2], h[3]};
  *(us4*)(pb + base + 1024 + tid * 4) = (us4){h[4], h[5], h[6], h[7]};
}

extern "C" void kernel_launch(void* const* d_in, const int* in_sizes, int n_in,
                              void* d_out, int out_size, void* d_ws, size_t ws_size,
                              hipStream_t stream) {
  const float* x  = (const float*)d_in[0];
  const float* Wq = (const float*)d_in[1];
  const float* bq = (const float*)d_in[2];
  const float* Wk = (const float*)d_in[3];
  const float* bk = (const float*)d_in[4];
  const float* Wv = (const float*)d_in[5];
  const float* bv = (const float*)d_in[6];
  float* out = (float*)d_out;
  char* ws = (char*)d_ws;
  const size_t MB = 1024 * 1024;
  // Layout (134 MiB; qb/kb/vtmp contiguous = qkv output base):
  //  [0,16)  qb   [16,32) kb   [32,48) vtmp
  //  [48,54) wtb  [54,70) xb   [70,86) vtb
  //  [86,118) scores fp16      [118,134) pb
  us* qb   = (us*)(ws + 0 * MB);
  us* kb   = (us*)(ws + 16 * MB);
  us* vtmp = (us*)(ws + 32 * MB);
  us* wtb  = (us*)(ws + 48 * MB);
  us* xb   = (us*)(ws + 54 * MB);
  us* vtb  = (us*)(ws + 70 * MB);
  _Float16* scores = (_Float16*)(ws + 86 * MB);
  us* pb   = (us*)(ws + 118 * MB);
  (void)vtmp;

  wt_prep<<<dim3(16, 16, 3), 256, 0, stream>>>(Wq, Wk, Wv, wtb);
  xcast<<<dim3(4096), 256, 0, stream>>>(x, xb);
  // qkv: M=8192 x N=3072 (3 mats) x K=1024
  gemm32<0, 128, 256, 4><<<dim3(64, 12, 1), 512, 0, stream>>>(
      xb, wtb, 0, 0, D_, D_, 32, bq, bk, bv, qb);
  vtrans<<<dim3(16, 32, 4), 256, 0, stream>>>(vtmp, vtb);
  // s2: per batch M=2048 x N=2048 x K=1024
  gemm32<1, 128, 256, 4><<<dim3(16, 8, 4), 512, 0, stream>>>(
      qb, kb, (size_t)S_ * D_, (size_t)S_ * D_, D_, D_, 32,
      nullptr, nullptr, nullptr, scores);
  softmax_k<<<dim3(B_ * S_), 256, 0, stream>>>(scores, pb);
  // s3: per batch M=2048 x N=1024 x K=2048, 256x128 tiles
  gemm32<2, 256, 128, 2><<<dim3(8, 8, 4), 512, 0, stream>>>(
      pb, vtb, (size_t)S_ * S_, (size_t)D_ * S_, S_, S_, 64,
      nullptr, nullptr, nullptr, out);
}

// Round 7
// 169.938 us; speedup vs baseline: 1.0163x; 1.0163x over previous
//
#include <hip/hip_runtime.h>
#include <hip/hip_bf16.h>
#include <stdint.h>

// SelfAttention: x[4,2048,1024] fp32; q=xWq+bq, k=xWk+bk, v=xWv+bv;
// out = softmax(q k^T / 32) v.
// R7: faithful 8-phase 256x256 GEMM (T2 swizzle + T3/T4 counted vmcnt + T5
// setprio): BK=64, 8 waves (2x4), wave-tile 128x64, LDS = 5 x 32KiB
// half-buffers (160KB, mod-5 rotation, stage 3 halves ahead, vmcnt(4)).
// qkv epilogue writes v transposed directly (vtrans kernel deleted).
// s3 keeps the proven R5 gemm8p (256x128, 3-buffer) verbatim.

typedef short bf16x8 __attribute__((ext_vector_type(8)));
typedef float f32x4 __attribute__((ext_vector_type(4)));
typedef unsigned short us4 __attribute__((ext_vector_type(4)));
typedef _Float16 h4 __attribute__((ext_vector_type(4)));
typedef unsigned short us;

#define B_ 4
#define S_ 2048
#define D_ 1024

__device__ __forceinline__ us f2bf(float f) {
  unsigned int u = __float_as_uint(f);
  unsigned int r = (u + 0x7fffu + ((u >> 16) & 1u)) >> 16;  // RNE
  return (us)r;
}

// async global->LDS: lds arg = WAVE-UNIFORM base; HW adds lane*16. src per-lane.
__device__ __forceinline__ void gl2lds16(void* lds, const void* g) {
  __builtin_amdgcn_global_load_lds(
      (const __attribute__((address_space(1))) unsigned int*)(uintptr_t)g,
      (__attribute__((address_space(3))) unsigned int*)(uintptr_t)lds,
      16, 0, 0);
}

__device__ __forceinline__ void sched_fence() { __builtin_amdgcn_sched_barrier(0); }
__device__ __forceinline__ void barrier_f() {
  sched_fence(); __builtin_amdgcn_s_barrier(); sched_fence();
}

// ==================== 8-phase 256x256 kernel ====================
// LDS: 5 half-buffers of 32KB. HB[j]: A-part [128][128B] then B-part [128][128B].
// half h = 2t+i: rows [i*128, i*128+128) of A and of B, K-range of tile t.
// Swizzle (proven R5): LDS[row][slot] = G[row][slot ^ (row&7)], 16B slots.
// EPI: 0 = qkv (bf16 q/k + bias; v written transposed), 1 = s2 (fp16, *1/32)
template<int EPI>
__global__ __launch_bounds__(512, 2) void gemm256(
    const us* __restrict__ Aall, const us* __restrict__ Ball,
    size_t aBatch, size_t bBatch, int sAe, int sBe, int nt,
    const float* __restrict__ bq, const float* __restrict__ bk,
    const float* __restrict__ bv, void* __restrict__ outp,
    us* __restrict__ vtb) {
  __shared__ __align__(16) us lds[5 * 16384];  // 160 KiB
  const int tid = threadIdx.x, lane = tid & 63, wave = tid >> 6;
  const int wm = wave >> 2, wn = wave & 3;     // 2 x 4 waves, 128x64 each
  const int m0 = blockIdx.x * 256, n0 = blockIdx.y * 256;
  const size_t bz = blockIdx.z;
  const char* gA = (const char*)(Aall + bz * aBatch + (size_t)m0 * sAe);
  const char* gB = (const char*)(Ball + bz * bBatch + (size_t)n0 * sBe);
  const size_t sA = (size_t)sAe * 2, sB = (size_t)sBe * 2;

  const int r15 = lane & 15, kg = lane >> 4;
  const int srcslot = ((lane & 7) ^ (lane >> 3)) << 4;  // involution w/ row&7
  const int ldl = lane >> 3;
  const int brow = (wn & 1) * 64;
  const int nh = 2 * nt;

  // stage chunk c (0..3) of half h: c<2 -> A local rows c*64.., else B (c-2)*64..
  auto stage = [&](int h, int c) {
    char* dst = (char*)lds + (h % 5) * 32768 +
                (c < 2 ? c * 8192 : 16384 + (c - 2) * 8192) + wave * 1024;
    int row = (h & 1) * 128 + (c < 2 ? c * 64 : (c - 2) * 64) + wave * 8 + ldl;
    const char* src = (c < 2 ? gA + (size_t)row * sA : gB + (size_t)row * sB) +
                      (size_t)(h >> 1) * 128 + srcslot;
    gl2lds16(dst, src);
  };

  // prologue: halves 0,1,2 (12 chunks)
#pragma unroll
  for (int h = 0; h < 3; ++h)
#pragma unroll
    for (int c = 0; c < 4; ++c) stage(h, c);
  asm volatile("s_waitcnt vmcnt(4)" ::: "memory");  // halves 0,1 landed
  barrier_f();

  f32x4 acc[8][4] = {};
  for (int t = 0; t < nt; ++t) {
    const char* hbA = (const char*)lds + ((2 * t + wm) % 5) * 32768;
    const char* hbB = (const char*)lds + ((2 * t + (wn >> 1)) % 5) * 32768 + 16384;
    const int hs_base = 2 * t + 3;
    bf16x8 Br[4];
#pragma unroll
    for (int p = 0; p < 4; ++p) {
      const int kh = p >> 1, mq = p & 1;
      // ---- ds_reads for this phase's 16-MFMA cluster ----
      bf16x8 Ar[4];
#pragma unroll
      for (int f = 0; f < 4; ++f) {
        int lr = (mq * 4 + f) * 16 + r15;
        Ar[f] = *(const bf16x8*)(hbA + lr * 128 +
                                 ((((kh << 2) | kg) ^ (lr & 7)) << 4));
      }
      if (mq == 0) {
#pragma unroll
        for (int n = 0; n < 4; ++n) {
          int lr = brow + n * 16 + r15;
          Br[n] = *(const bf16x8*)(hbB + lr * 128 +
                                   ((((kh << 2) | kg) ^ (lr & 7)) << 4));
        }
      }
      // ---- stage 2 chunks (halves 2t+3, 2t+4 = 3 ahead) ----
      {
        int cp = p * 2;
        int h1 = hs_base + (cp >> 2);
        if (h1 < nh) stage(h1, cp & 3);
        int h2 = hs_base + ((cp + 1) >> 2);
        if (h2 < nh) stage(h2, (cp + 1) & 3);
      }
      barrier_f();
      __builtin_amdgcn_s_setprio(1);
#pragma unroll
      for (int n = 0; n < 4; ++n)
#pragma unroll
        for (int f = 0; f < 4; ++f)
          acc[mq * 4 + f][n] = __builtin_amdgcn_mfma_f32_16x16x32_bf16(
              Ar[f], Br[n], acc[mq * 4 + f][n], 0, 0, 0);
      __builtin_amdgcn_s_setprio(0);
      if (p == 3) {
        // counted drain: tile t+1 (halves 2t+2,2t+3) landed; 2t+4 stays in flight
        if (t <= nt - 3) asm volatile("s_waitcnt vmcnt(4)" ::: "memory");
        else             asm volatile("s_waitcnt vmcnt(0)" ::: "memory");
      }
      barrier_f();
    }
  }

#pragma unroll
  for (int fm = 0; fm < 8; ++fm)
#pragma unroll
    for (int fn = 0; fn < 4; ++fn) {
      int col = n0 + wn * 64 + fn * 16 + r15;
      int row0 = m0 + wm * 128 + fm * 16 + ((lane >> 4) << 2);
      if constexpr (EPI == 0) {
        int mat = col >> 10;
        const float* bp = (mat == 0) ? bq : (mat == 1) ? bk : bv;
        float bb = bp[col & 1023];
        if (mat < 2) {
          us* ob = (us*)outp + ((size_t)mat << 23);
#pragma unroll
          for (int r = 0; r < 4; ++r)
            ob[(size_t)(row0 + r) * D_ + (col & 1023)] = f2bf(acc[fm][fn][r] + bb);
        } else {
          // v written transposed: vtb[b][d][t]
          int b = row0 >> 11, trow = row0 & 2047, dcol = col & 1023;
          us4 v4 = {f2bf(acc[fm][fn][0] + bb), f2bf(acc[fm][fn][1] + bb),
                    f2bf(acc[fm][fn][2] + bb), f2bf(acc[fm][fn][3] + bb)};
          *(us4*)(vtb + (size_t)b * D_ * S_ + (size_t)dcol * S_ + trow) = v4;
        }
      } else {
        _Float16* sc = (_Float16*)outp + bz * (size_t)(S_ * S_);
#pragma unroll
        for (int r = 0; r < 4; ++r)
          sc[(size_t)(row0 + r) * S_ + col] = (_Float16)(acc[fm][fn][r] * 0.03125f);
      }
    }
}

// ==================== R5 gemm8p (proven) for s3 ====================
template<int BM, int R0, int R1>
__device__ __forceinline__ void stageR(us* buf, const us* gA, size_t sA,
                                       const us* gB, size_t sB,
                                       int wave, int lane) {
  int slot = ((lane & 7) ^ (lane >> 3)) << 4;
  char* l = (char*)buf;
#pragma unroll
  for (int r = R0; r < R1; ++r) {
    int row = r * 64 + wave * 8 + (lane >> 3);
    const char* src;
    if (r * 64 < BM)
      src = (const char*)gA + (size_t)row * sA + slot;
    else
      src = (const char*)gB + (size_t)(row - BM) * sB + slot;
    gl2lds16(l + r * 8192 + wave * 1024, src);
  }
}

template<int EPI, int BM, int BN, int WMS, int WNS>
__global__ __launch_bounds__(512, 2) void gemm8p(
    const us* __restrict__ Aall, const us* __restrict__ Ball,
    size_t aBatch, size_t bBatch, int sAe, int sBe, int nt,
    void* __restrict__ outp) {
  __shared__ __align__(16) us lds[3][(BM + BN) * 64];
  int tid = threadIdx.x, lane = tid & 63, wave = tid >> 6;
  int wm = wave / WNS, wn = wave % WNS;
  int m0 = blockIdx.x * BM, n0 = blockIdx.y * BN;
  size_t bz = blockIdx.z;
  const us* gA = Aall + bz * aBatch + (size_t)m0 * sAe;
  const us* gB = Ball + bz * bBatch + (size_t)n0 * sBe;
  size_t sA = (size_t)sAe * 2, sB = (size_t)sBe * 2;

  stageR<BM, 0, 6>(lds[0], gA, sA, gB, sB, wave, lane);
  stageR<BM, 0, 6>(lds[1], gA + 64, sA, gB + 64, sB, wave, lane);

  int r15 = lane & 15, kg = lane >> 4, l7 = lane & 7;
  int x0 = (kg ^ l7) << 4;
  f32x4 acc[4][4] = {};

  for (int t = 0; t < nt; ++t) {
    if (t == nt - 1) asm volatile("s_waitcnt vmcnt(0)" ::: "memory");
    else             asm volatile("s_waitcnt vmcnt(6)" ::: "memory");
    barrier_f();
    const us* buf = lds[t % 3];
    us* nbuf = (us*)lds[(t + 2) % 3];
    bool dostage = (t + 2 < nt);
    const us* gA2 = gA + (size_t)(t + 2) * 64;
    const us* gB2 = gB + (size_t)(t + 2) * 64;
    const char* pa = (const char*)buf + (size_t)(wm * 64 + r15) * 128;
    const char* pb = (const char*)buf + (size_t)(BM + wn * 64 + r15) * 128;

    if (dostage) stageR<BM, 0, 3>(nbuf, gA2, sA, gB2, sB, wave, lane);
    bf16x8 A0[4], B0[4];
#pragma unroll
    for (int f = 0; f < 4; ++f) A0[f] = *(const bf16x8*)(pa + f * 2048 + x0);
#pragma unroll
    for (int f = 0; f < 4; ++f) B0[f] = *(const bf16x8*)(pb + f * 2048 + x0);
    __builtin_amdgcn_s_setprio(1);
#pragma unroll
    for (int fn = 0; fn < 4; ++fn)
#pragma unroll
      for (int fm = 0; fm < 4; ++fm)
        acc[fm][fn] = __builtin_amdgcn_mfma_f32_16x16x32_bf16(A0[fm], B0[fn], acc[fm][fn], 0, 0, 0);
    __builtin_amdgcn_s_setprio(0);

    if (dostage) stageR<BM, 3, 6>(nbuf, gA2, sA, gB2, sB, wave, lane);
    bf16x8 A1[4], B1[4];
#pragma unroll
    for (int f = 0; f < 4; ++f) A1[f] = *(const bf16x8*)(pa + f * 2048 + (x0 ^ 64));
#pragma unroll
    for (int f = 0; f < 4; ++f) B1[f] = *(const bf16x8*)(pb + f * 2048 + (x0 ^ 64));
    __builtin_amdgcn_s_setprio(1);
#pragma unroll
    for (int fn = 0; fn < 4; ++fn)
#pragma unroll
      for (int fm = 0; fm < 4; ++fm)
        acc[fm][fn] = __builtin_amdgcn_mfma_f32_16x16x32_bf16(A1[fm], B1[fn], acc[fm][fn], 0, 0, 0);
    __builtin_amdgcn_s_setprio(0);
  }

#pragma unroll
  for (int fm = 0; fm < 4; ++fm)
#pragma unroll
    for (int fn = 0; fn < 4; ++fn) {
      int col = n0 + wn * 64 + fn * 16 + r15;
      int row0 = m0 + wm * 64 + fm * 16 + ((lane >> 4) << 2);
      float* ob = (float*)outp + bz * (size_t)(S_ * D_);
#pragma unroll
      for (int r = 0; r < 4; ++r)
        ob[(size_t)(row0 + r) * D_ + col] = acc[fm][fn][r];
    }
}

// ---------------- W [k][n] fp32 -> Wt bf16 [n][k] (n = mat*1024 + col) ----------------
__global__ __launch_bounds__(256) void wt_prep(const float* __restrict__ Wq,
                                               const float* __restrict__ Wk,
                                               const float* __restrict__ Wv,
                                               us* __restrict__ wtb) {
  __shared__ us hs[64][65];
  int mat = blockIdx.z;
  const float* W = (mat == 0) ? Wq : (mat == 1) ? Wk : Wv;
  int n0 = blockIdx.x * 64, k0 = blockIdx.y * 64;
  int tid = threadIdx.x;
#pragma unroll
  for (int i = 0; i < 16; ++i) {
    int idx = tid + i * 256;
    int r = idx >> 6, c = idx & 63;
    hs[r][c] = f2bf(W[(size_t)(k0 + r) * D_ + (n0 + c)]);
  }
  __syncthreads();
  us* o = wtb + ((size_t)mat << 20);
#pragma unroll
  for (int i = 0; i < 16; ++i) {
    int idx = tid + i * 256;
    int r = idx >> 6, c = idx & 63;
    o[(size_t)(n0 + r) * D_ + (k0 + c)] = hs[c][r];
  }
}

// ---------------- x fp32 -> xb bf16 ----------------
__global__ __launch_bounds__(256) void xcast(const float* __restrict__ x,
                                             us* __restrict__ xb) {
  size_t i = ((size_t)blockIdx.x * 256 + threadIdx.x) * 8;
  float4 f0 = *(const float4*)(x + i);
  float4 f1 = *(const float4*)(x + i + 4);
  float vals[8] = {f0.x, f0.y, f0.z, f0.w, f1.x, f1.y, f1.z, f1.w};
  union { bf16x8 v; us s_[8]; } H;
#pragma unroll
  for (int e = 0; e < 8; ++e) H.s_[e] = f2bf(vals[e]);
  *(bf16x8*)(xb + i) = H.v;
}

// ---------------- row softmax: fp16 scores -> P bf16 ----------------
__global__ __launch_bounds__(256) void softmax_k(const _Float16* __restrict__ scores,
                                                 us* __restrict__ pb) {
  int row = blockIdx.x, tid = threadIdx.x, lane = tid & 63, wave = tid >> 6;
  const _Float16* s = scores + (size_t)row * S_;
  h4 a4 = ((const h4*)s)[tid];
  h4 b4 = ((const h4*)s)[256 + tid];
  float a[8] = {(float)a4.x, (float)a4.y, (float)a4.z, (float)a4.w,
                (float)b4.x, (float)b4.y, (float)b4.z, (float)b4.w};
  float m = a[0];
#pragma unroll
  for (int e = 1; e < 8; ++e) m = fmaxf(m, a[e]);
#pragma unroll
  for (int o = 32; o; o >>= 1) m = fmaxf(m, __shfl_xor(m, o));
  __shared__ float red[4];
  if (lane == 0) red[wave] = m;
  __syncthreads();
  m = fmaxf(fmaxf(red[0], red[1]), fmaxf(red[2], red[3]));
  float p[8];
  float sum = 0.f;
#pragma unroll
  for (int e = 0; e < 8; ++e) { p[e] = expf(a[e] - m); sum += p[e]; }
#pragma unroll
  for (int o = 32; o; o >>= 1) sum += __shfl_xor(sum, o);
  __syncthreads();
  if (lane == 0) red[wave] = sum;
  __syncthreads();
  float inv = 1.0f / (red[0] + red[1] + red[2] + red[3]);
  us h[8];
#pragma unroll
  for (int e = 0; e < 8; ++e) h[e] = f2bf(p[e] * inv);
  size_t base = (size_t)row * S_;
  *(us4*)(pb + base + tid * 4) = (us4){h[0], h[1], h[2], h[3]};
  *(us4*)(pb + base + 1024 + tid * 4) = (us4){h[4], h[5], h[6], h[7]};
}

extern "C" void kernel_launch(void* const* d_in, const int* in_sizes, int n_in,
                              void* d_out, int out_size, void* d_ws, size_t ws_size,
                              hipStream_t stream) {
  const float* x  = (const float*)d_in[0];
  const float* Wq = (const float*)d_in[1];
  const float* bq = (const float*)d_in[2];
  const float* Wk = (const float*)d_in[3];
  const float* bk = (const float*)d_in[4];
  const float* Wv = (const float*)d_in[5];
  const float* bv = (const float*)d_in[6];
  float* out = (float*)d_out;
  char* ws = (char*)d_ws;
  const size_t MB = 1024 * 1024;
  // Layout (118 MiB): qb [0,16) kb [16,32) vtb [32,48) wtb [48,54)
  //                   xb [54,70) scores [70,102) pb [102,118)
  us* qb   = (us*)(ws + 0 * MB);
  us* vtb  = (us*)(ws + 32 * MB);
  us* wtb  = (us*)(ws + 48 * MB);
  us* xb   = (us*)(ws + 54 * MB);
  _Float16* scores = (_Float16*)(ws + 70 * MB);
  us* pb   = (us*)(ws + 102 * MB);
  us* kb   = (us*)(ws + 16 * MB);

  wt_prep<<<dim3(16, 16, 3), 256, 0, stream>>>(Wq, Wk, Wv, wtb);
  xcast<<<dim3(4096), 256, 0, stream>>>(x, xb);
  // qkv: M=8192 x N=3072 x K=1024; v written transposed to vtb
  gemm256<0><<<dim3(32, 12, 1), 512, 0, stream>>>(
      xb, wtb, 0, 0, D_, D_, 16, bq, bk, bv, qb, vtb);
  // s2: per batch 2048 x 2048 x 1024
  gemm256<1><<<dim3(8, 8, 4), 512, 0, stream>>>(
      qb, kb, (size_t)S_ * D_, (size_t)S_ * D_, D_, D_, 16,
      nullptr, nullptr, nullptr, scores, nullptr);
  softmax_k<<<dim3(B_ * S_), 256, 0, stream>>>(scores, pb);
  // s3: per batch 2048 x 1024 x 2048 (proven R5 kernel)
  gemm8p<2, 256, 128, 4, 2><<<dim3(8, 8, 4), 512, 0, stream>>>(
      pb, vtb, (size_t)S_ * S_, (size_t)D_ * S_, S_, S_, 32, out);
}

// Round 8
// 165.055 us; speedup vs baseline: 1.0464x; 1.0296x over previous
//
#include <hip/hip_runtime.h>
#include <hip/hip_bf16.h>
#include <stdint.h>

// SelfAttention: x[4,2048,1024] fp32; q=xWq+bq, k=xWk+bk, v=xWv+bv;
// out = softmax(q k^T / 32) v.
// R8: R5's proven single-barrier 3-buffer loop + 128x64 wave-tiles
// (BM=BN=256, BK=32, 8 waves 2x4, 96KiB LDS, 42.7 FLOP/LDS-byte vs R5's 32).
// Swizzle for 64B rows: read slot = kg ^ ((row>>1)&3); stage src slot =
// (lane&3) ^ ((lane>>3)&3) (lane-only involution). v-transpose epilogue kept.
// s3 stays on the proven R5 gemm8p.

typedef short bf16x8 __attribute__((ext_vector_type(8)));
typedef float f32x4 __attribute__((ext_vector_type(4)));
typedef unsigned short us4 __attribute__((ext_vector_type(4)));
typedef _Float16 h4 __attribute__((ext_vector_type(4)));
typedef unsigned short us;

#define B_ 4
#define S_ 2048
#define D_ 1024

__device__ __forceinline__ us f2bf(float f) {
  unsigned int u = __float_as_uint(f);
  unsigned int r = (u + 0x7fffu + ((u >> 16) & 1u)) >> 16;  // RNE
  return (us)r;
}

// async global->LDS: lds arg = WAVE-UNIFORM base; HW adds lane*16. src per-lane.
__device__ __forceinline__ void gl2lds16(void* lds, const void* g) {
  __builtin_amdgcn_global_load_lds(
      (const __attribute__((address_space(1))) unsigned int*)(uintptr_t)g,
      (__attribute__((address_space(3))) unsigned int*)(uintptr_t)lds,
      16, 0, 0);
}

__device__ __forceinline__ void sched_fence() { __builtin_amdgcn_sched_barrier(0); }
__device__ __forceinline__ void barrier_f() {
  sched_fence(); __builtin_amdgcn_s_barrier(); sched_fence();
}

// ==================== R8 kernel: 256x256, BK=32, 8 waves (2x4) ====================
// Buffer: 512 rows x 64B (A rows 0..255 = tile M, B rows 256..511 = tile N).
// LDS[row][slot ^ g(row)] = G[row][slot], g(row) = (row>>1)&3 (16B slots).
// Stage: 4 rounds of 128 rows; thread -> row r*128 + wave*16 + (lane>>2),
// src slot = (lane&3) ^ ((lane>>3)&3)  [= (lane&3) ^ ((row>>1)&3)].
template<int EPI>
__global__ __launch_bounds__(512, 2) void gemm256k(
    const us* __restrict__ Aall, const us* __restrict__ Ball,
    size_t aBatch, size_t bBatch, int sAe, int sBe, int nt,
    const float* __restrict__ bq, const float* __restrict__ bk,
    const float* __restrict__ bv, void* __restrict__ outp,
    us* __restrict__ vtb) {
  __shared__ __align__(16) us lds3[3][16384];   // 3 x 32 KiB
  const int tid = threadIdx.x, lane = tid & 63, wave = tid >> 6;
  const int wm = wave >> 2, wn = wave & 3;      // wave-tile 128x64
  const int m0 = blockIdx.x * 256, n0 = blockIdx.y * 256;
  const size_t bz = blockIdx.z;
  const char* gA = (const char*)(Aall + bz * aBatch + (size_t)m0 * sAe);
  const char* gB = (const char*)(Ball + bz * bBatch + (size_t)n0 * sBe);
  const size_t sA = (size_t)sAe * 2, sB = (size_t)sBe * 2;

  const int r15 = lane & 15, kg = lane >> 4;
  const int srcslot = (((lane & 3) ^ ((lane >> 3) & 3)) << 4);
  const int srow = wave * 16 + (lane >> 2);     // staging row within round

  auto stage = [&](int bi, int t) {
    char* l = (char*)lds3[bi];
    const size_t koff = (size_t)t * 64;         // BK=32 -> 64 bytes
#pragma unroll
    for (int r = 0; r < 4; ++r) {
      int row = r * 128 + srow;
      const char* src = (row < 256)
          ? gA + (size_t)row * sA + koff + srcslot
          : gB + (size_t)(row - 256) * sB + koff + srcslot;
      gl2lds16(l + r * 8192 + wave * 1024, src);
    }
  };

  // prologue: tiles 0,1 staged (4 loads each)
  stage(0, 0);
  stage(1, 1);

  f32x4 acc[8][4] = {};
  for (int t = 0; t < nt; ++t) {
    if (t == nt - 1) asm volatile("s_waitcnt vmcnt(0)" ::: "memory");
    else             asm volatile("s_waitcnt vmcnt(4)" ::: "memory");
    barrier_f();    // tile-t staged by all waves; all t-1 reads consumed
    if (t + 2 < nt) stage((t + 2) % 3, t + 2);
    const char* buf = (const char*)lds3[t % 3];

    bf16x8 Af[8], Bf[4];
#pragma unroll
    for (int f = 0; f < 8; ++f) {
      int tr = wm * 128 + f * 16 + r15;
      Af[f] = *(const bf16x8*)(buf + tr * 64 + ((kg ^ ((tr >> 1) & 3)) << 4));
    }
#pragma unroll
    for (int n = 0; n < 4; ++n) {
      int tr = 256 + wn * 64 + n * 16 + r15;
      Bf[n] = *(const bf16x8*)(buf + tr * 64 + ((kg ^ ((tr >> 1) & 3)) << 4));
    }
    __builtin_amdgcn_s_setprio(1);
#pragma unroll
    for (int n = 0; n < 4; ++n)
#pragma unroll
      for (int f = 0; f < 8; ++f)
        acc[f][n] = __builtin_amdgcn_mfma_f32_16x16x32_bf16(Af[f], Bf[n], acc[f][n], 0, 0, 0);
    __builtin_amdgcn_s_setprio(0);
  }

#pragma unroll
  for (int fm = 0; fm < 8; ++fm)
#pragma unroll
    for (int fn = 0; fn < 4; ++fn) {
      int col = n0 + wn * 64 + fn * 16 + r15;
      int row0 = m0 + wm * 128 + fm * 16 + ((lane >> 4) << 2);
      if constexpr (EPI == 0) {
        int mat = col >> 10;
        const float* bp = (mat == 0) ? bq : (mat == 1) ? bk : bv;
        float bb = bp[col & 1023];
        if (mat < 2) {
          us* ob = (us*)outp + ((size_t)mat << 23);
#pragma unroll
          for (int r = 0; r < 4; ++r)
            ob[(size_t)(row0 + r) * D_ + (col & 1023)] = f2bf(acc[fm][fn][r] + bb);
        } else {
          // v written transposed: vtb[b][d][t]  (verified R7)
          int b = row0 >> 11, trow = row0 & 2047, dcol = col & 1023;
          us4 v4 = {f2bf(acc[fm][fn][0] + bb), f2bf(acc[fm][fn][1] + bb),
                    f2bf(acc[fm][fn][2] + bb), f2bf(acc[fm][fn][3] + bb)};
          *(us4*)(vtb + (size_t)b * D_ * S_ + (size_t)dcol * S_ + trow) = v4;
        }
      } else {
        _Float16* sc = (_Float16*)outp + bz * (size_t)(S_ * S_);
#pragma unroll
        for (int r = 0; r < 4; ++r)
          sc[(size_t)(row0 + r) * S_ + col] = (_Float16)(acc[fm][fn][r] * 0.03125f);
      }
    }
}

// ==================== R5 gemm8p (proven) for s3 ====================
template<int BM, int R0, int R1>
__device__ __forceinline__ void stageR(us* buf, const us* gA, size_t sA,
                                       const us* gB, size_t sB,
                                       int wave, int lane) {
  int slot = ((lane & 7) ^ (lane >> 3)) << 4;
  char* l = (char*)buf;
#pragma unroll
  for (int r = R0; r < R1; ++r) {
    int row = r * 64 + wave * 8 + (lane >> 3);
    const char* src;
    if (r * 64 < BM)
      src = (const char*)gA + (size_t)row * sA + slot;
    else
      src = (const char*)gB + (size_t)(row - BM) * sB + slot;
    gl2lds16(l + r * 8192 + wave * 1024, src);
  }
}

template<int EPI, int BM, int BN, int WMS, int WNS>
__global__ __launch_bounds__(512, 2) void gemm8p(
    const us* __restrict__ Aall, const us* __restrict__ Ball,
    size_t aBatch, size_t bBatch, int sAe, int sBe, int nt,
    void* __restrict__ outp) {
  __shared__ __align__(16) us lds[3][(BM + BN) * 64];
  int tid = threadIdx.x, lane = tid & 63, wave = tid >> 6;
  int wm = wave / WNS, wn = wave % WNS;
  int m0 = blockIdx.x * BM, n0 = blockIdx.y * BN;
  size_t bz = blockIdx.z;
  const us* gA = Aall + bz * aBatch + (size_t)m0 * sAe;
  const us* gB = Ball + bz * bBatch + (size_t)n0 * sBe;
  size_t sA = (size_t)sAe * 2, sB = (size_t)sBe * 2;

  stageR<BM, 0, 6>(lds[0], gA, sA, gB, sB, wave, lane);
  stageR<BM, 0, 6>(lds[1], gA + 64, sA, gB + 64, sB, wave, lane);

  int r15 = lane & 15, kg = lane >> 4, l7 = lane & 7;
  int x0 = (kg ^ l7) << 4;
  f32x4 acc[4][4] = {};

  for (int t = 0; t < nt; ++t) {
    if (t == nt - 1) asm volatile("s_waitcnt vmcnt(0)" ::: "memory");
    else             asm volatile("s_waitcnt vmcnt(6)" ::: "memory");
    barrier_f();
    const us* buf = lds[t % 3];
    us* nbuf = (us*)lds[(t + 2) % 3];
    bool dostage = (t + 2 < nt);
    const us* gA2 = gA + (size_t)(t + 2) * 64;
    const us* gB2 = gB + (size_t)(t + 2) * 64;
    const char* pa = (const char*)buf + (size_t)(wm * 64 + r15) * 128;
    const char* pb = (const char*)buf + (size_t)(BM + wn * 64 + r15) * 128;

    if (dostage) stageR<BM, 0, 3>(nbuf, gA2, sA, gB2, sB, wave, lane);
    bf16x8 A0[4], B0[4];
#pragma unroll
    for (int f = 0; f < 4; ++f) A0[f] = *(const bf16x8*)(pa + f * 2048 + x0);
#pragma unroll
    for (int f = 0; f < 4; ++f) B0[f] = *(const bf16x8*)(pb + f * 2048 + x0);
    __builtin_amdgcn_s_setprio(1);
#pragma unroll
    for (int fn = 0; fn < 4; ++fn)
#pragma unroll
      for (int fm = 0; fm < 4; ++fm)
        acc[fm][fn] = __builtin_amdgcn_mfma_f32_16x16x32_bf16(A0[fm], B0[fn], acc[fm][fn], 0, 0, 0);
    __builtin_amdgcn_s_setprio(0);

    if (dostage) stageR<BM, 3, 6>(nbuf, gA2, sA, gB2, sB, wave, lane);
    bf16x8 A1[4], B1[4];
#pragma unroll
    for (int f = 0; f < 4; ++f) A1[f] = *(const bf16x8*)(pa + f * 2048 + (x0 ^ 64));
#pragma unroll
    for (int f = 0; f < 4; ++f) B1[f] = *(const bf16x8*)(pb + f * 2048 + (x0 ^ 64));
    __builtin_amdgcn_s_setprio(1);
#pragma unroll
    for (int fn = 0; fn < 4; ++fn)
#pragma unroll
      for (int fm = 0; fm < 4; ++fm)
        acc[fm][fn] = __builtin_amdgcn_mfma_f32_16x16x32_bf16(A1[fm], B1[fn], acc[fm][fn], 0, 0, 0);
    __builtin_amdgcn_s_setprio(0);
  }

#pragma unroll
  for (int fm = 0; fm < 4; ++fm)
#pragma unroll
    for (int fn = 0; fn < 4; ++fn) {
      int col = n0 + wn * 64 + fn * 16 + r15;
      int row0 = m0 + wm * 64 + fm * 16 + ((lane >> 4) << 2);
      float* ob = (float*)outp + bz * (size_t)(S_ * D_);
#pragma unroll
      for (int r = 0; r < 4; ++r)
        ob[(size_t)(row0 + r) * D_ + col] = acc[fm][fn][r];
    }
}

// ---------------- W [k][n] fp32 -> Wt bf16 [n][k] (n = mat*1024 + col) ----------------
__global__ __launch_bounds__(256) void wt_prep(const float* __restrict__ Wq,
                                               const float* __restrict__ Wk,
                                               const float* __restrict__ Wv,
                                               us* __restrict__ wtb) {
  __shared__ us hs[64][65];
  int mat = blockIdx.z;
  const float* W = (mat == 0) ? Wq : (mat == 1) ? Wk : Wv;
  int n0 = blockIdx.x * 64, k0 = blockIdx.y * 64;
  int tid = threadIdx.x;
#pragma unroll
  for (int i = 0; i < 16; ++i) {
    int idx = tid + i * 256;
    int r = idx >> 6, c = idx & 63;
    hs[r][c] = f2bf(W[(size_t)(k0 + r) * D_ + (n0 + c)]);
  }
  __syncthreads();
  us* o = wtb + ((size_t)mat << 20);
#pragma unroll
  for (int i = 0; i < 16; ++i) {
    int idx = tid + i * 256;
    int r = idx >> 6, c = idx & 63;
    o[(size_t)(n0 + r) * D_ + (k0 + c)] = hs[c][r];
  }
}

// ---------------- x fp32 -> xb bf16 ----------------
__global__ __launch_bounds__(256) void xcast(const float* __restrict__ x,
                                             us* __restrict__ xb) {
  size_t i = ((size_t)blockIdx.x * 256 + threadIdx.x) * 8;
  float4 f0 = *(const float4*)(x + i);
  float4 f1 = *(const float4*)(x + i + 4);
  float vals[8] = {f0.x, f0.y, f0.z, f0.w, f1.x, f1.y, f1.z, f1.w};
  union { bf16x8 v; us s_[8]; } H;
#pragma unroll
  for (int e = 0; e < 8; ++e) H.s_[e] = f2bf(vals[e]);
  *(bf16x8*)(xb + i) = H.v;
}

// ---------------- row softmax: fp16 scores -> P bf16 ----------------
__global__ __launch_bounds__(256) void softmax_k(const _Float16* __restrict__ scores,
                                                 us* __restrict__ pb) {
  int row = blockIdx.x, tid = threadIdx.x, lane = tid & 63, wave = tid >> 6;
  const _Float16* s = scores + (size_t)row * S_;
  h4 a4 = ((const h4*)s)[tid];
  h4 b4 = ((const h4*)s)[256 + tid];
  float a[8] = {(float)a4.x, (float)a4.y, (float)a4.z, (float)a4.w,
                (float)b4.x, (float)b4.y, (float)b4.z, (float)b4.w};
  float m = a[0];
#pragma unroll
  for (int e = 1; e < 8; ++e) m = fmaxf(m, a[e]);
#pragma unroll
  for (int o = 32; o; o >>= 1) m = fmaxf(m, __shfl_xor(m, o));
  __shared__ float red[4];
  if (lane == 0) red[wave] = m;
  __syncthreads();
  m = fmaxf(fmaxf(red[0], red[1]), fmaxf(red[2], red[3]));
  float p[8];
  float sum = 0.f;
#pragma unroll
  for (int e = 0; e < 8; ++e) { p[e] = expf(a[e] - m); sum += p[e]; }
#pragma unroll
  for (int o = 32; o; o >>= 1) sum += __shfl_xor(sum, o);
  __syncthreads();
  if (lane == 0) red[wave] = sum;
  __syncthreads();
  float inv = 1.0f / (red[0] + red[1] + red[2] + red[3]);
  us h[8];
#pragma unroll
  for (int e = 0; e < 8; ++e) h[e] = f2bf(p[e] * inv);
  size_t base = (size_t)row * S_;
  *(us4*)(pb + base + tid * 4) = (us4){h[0], h[1], h[2], h[3]};
  *(us4*)(pb + base + 1024 + tid * 4) = (us4){h[4], h[5], h[6], h[7]};
}

extern "C" void kernel_launch(void* const* d_in, const int* in_sizes, int n_in,
                              void* d_out, int out_size, void* d_ws, size_t ws_size,
                              hipStream_t stream) {
  const float* x  = (const float*)d_in[0];
  const float* Wq = (const float*)d_in[1];
  const float* bq = (const float*)d_in[2];
  const float* Wk = (const float*)d_in[3];
  const float* bk = (const float*)d_in[4];
  const float* Wv = (const float*)d_in[5];
  const float* bv = (const float*)d_in[6];
  float* out = (float*)d_out;
  char* ws = (char*)d_ws;
  const size_t MB = 1024 * 1024;
  // Layout (118 MiB): qb [0,16) kb [16,32) vtb [32,48) wtb [48,54)
  //                   xb [54,70) scores [70,102) pb [102,118)
  us* qb   = (us*)(ws + 0 * MB);
  us* kb   = (us*)(ws + 16 * MB);
  us* vtb  = (us*)(ws + 32 * MB);
  us* wtb  = (us*)(ws + 48 * MB);
  us* xb   = (us*)(ws + 54 * MB);
  _Float16* scores = (_Float16*)(ws + 70 * MB);
  us* pb   = (us*)(ws + 102 * MB);

  wt_prep<<<dim3(16, 16, 3), 256, 0, stream>>>(Wq, Wk, Wv, wtb);
  xcast<<<dim3(4096), 256, 0, stream>>>(x, xb);
  // qkv: M=8192 x N=3072 x K=1024 (32 K-tiles); v written transposed to vtb
  gemm256k<0><<<dim3(32, 12, 1), 512, 0, stream>>>(
      xb, wtb, 0, 0, D_, D_, 32, bq, bk, bv, qb, vtb);
  // s2: per batch 2048 x 2048 x 1024
  gemm256k<1><<<dim3(8, 8, 4), 512, 0, stream>>>(
      qb, kb, (size_t)S_ * D_, (size_t)S_ * D_, D_, D_, 32,
      nullptr, nullptr, nullptr, scores, nullptr);
  softmax_k<<<dim3(B_ * S_), 256, 0, stream>>>(scores, pb);
  // s3: per batch 2048 x 1024 x 2048 (proven R5 kernel)
  gemm8p<2, 256, 128, 4, 2><<<dim3(8, 8, 4), 512, 0, stream>>>(
      pb, vtb, (size_t)S_ * S_, (size_t)D_ * S_, S_, S_, 32, out);
}

// Round 9
// 152.159 us; speedup vs baseline: 1.1351x; 1.0848x over previous
//
#include <hip/hip_runtime.h>
#include <hip/hip_bf16.h>
#include <stdint.h>

// SelfAttention: x[4,2048,1024] fp32; q=xWq+bq, k=xWk+bk, v=xWv+bv;
// out = softmax(q k^T / 32) v.
// R9: qkv back on the measured-best R5 gemm8p (128x256, BK=64, grid 768 = 3
// exact rounds) with fused bias + v-transpose epilogue (vtrans stays deleted).
// s2 on gemm256k (grid 256 exact), s3 on gemm8p<2>. softmax vectorized h8.

typedef short bf16x8 __attribute__((ext_vector_type(8)));
typedef float f32x4 __attribute__((ext_vector_type(4)));
typedef unsigned short us4 __attribute__((ext_vector_type(4)));
typedef unsigned short us8 __attribute__((ext_vector_type(8)));
typedef _Float16 h8v __attribute__((ext_vector_type(8)));
typedef unsigned short us;

#define B_ 4
#define S_ 2048
#define D_ 1024

__device__ __forceinline__ us f2bf(float f) {
  unsigned int u = __float_as_uint(f);
  unsigned int r = (u + 0x7fffu + ((u >> 16) & 1u)) >> 16;  // RNE
  return (us)r;
}

// async global->LDS: lds arg = WAVE-UNIFORM base; HW adds lane*16. src per-lane.
__device__ __forceinline__ void gl2lds16(void* lds, const void* g) {
  __builtin_amdgcn_global_load_lds(
      (const __attribute__((address_space(1))) unsigned int*)(uintptr_t)g,
      (__attribute__((address_space(3))) unsigned int*)(uintptr_t)lds,
      16, 0, 0);
}

__device__ __forceinline__ void sched_fence() { __builtin_amdgcn_sched_barrier(0); }
__device__ __forceinline__ void barrier_f() {
  sched_fence(); __builtin_amdgcn_s_barrier(); sched_fence();
}

// ==================== gemm8p: R5's proven 128x256 / 256x128, BK=64 ====================
// LDS [row][128B], swizzle LDS[row][slot ^ (row&7)] = G[row][slot] (16B slots).
template<int BM, int R0, int R1>
__device__ __forceinline__ void stageR(us* buf, const us* gA, size_t sA,
                                       const us* gB, size_t sB,
                                       int wave, int lane) {
  int slot = ((lane & 7) ^ (lane >> 3)) << 4;
  char* l = (char*)buf;
#pragma unroll
  for (int r = R0; r < R1; ++r) {
    int row = r * 64 + wave * 8 + (lane >> 3);
    const char* src;
    if (r * 64 < BM)
      src = (const char*)gA + (size_t)row * sA + slot;
    else
      src = (const char*)gB + (size_t)(row - BM) * sB + slot;
    gl2lds16(l + r * 8192 + wave * 1024, src);
  }
}

// EPI: 0 = qkv (bf16 q/k + bias; v written transposed to vtb), 2 = s3 (f32 out)
template<int EPI, int BM, int BN, int WNS>
__global__ __launch_bounds__(512, 2) void gemm8p(
    const us* __restrict__ Aall, const us* __restrict__ Ball,
    size_t aBatch, size_t bBatch, int sAe, int sBe, int nt,
    const float* __restrict__ bq, const float* __restrict__ bk,
    const float* __restrict__ bv, void* __restrict__ outp,
    us* __restrict__ vtb) {
  __shared__ __align__(16) us lds[3][(BM + BN) * 64];
  int tid = threadIdx.x, lane = tid & 63, wave = tid >> 6;
  int wm = wave / WNS, wn = wave % WNS;
  int m0 = blockIdx.x * BM, n0 = blockIdx.y * BN;
  size_t bz = blockIdx.z;
  const us* gA = Aall + bz * aBatch + (size_t)m0 * sAe;
  const us* gB = Ball + bz * bBatch + (size_t)n0 * sBe;
  size_t sA = (size_t)sAe * 2, sB = (size_t)sBe * 2;

  stageR<BM, 0, 6>(lds[0], gA, sA, gB, sB, wave, lane);
  stageR<BM, 0, 6>(lds[1], gA + 64, sA, gB + 64, sB, wave, lane);

  int r15 = lane & 15, kg = lane >> 4, l7 = lane & 7;
  int x0 = (kg ^ l7) << 4;
  f32x4 acc[4][4] = {};

  for (int t = 0; t < nt; ++t) {
    if (t == nt - 1) asm volatile("s_waitcnt vmcnt(0)" ::: "memory");
    else             asm volatile("s_waitcnt vmcnt(6)" ::: "memory");
    barrier_f();
    const us* buf = lds[t % 3];
    us* nbuf = (us*)lds[(t + 2) % 3];
    bool dostage = (t + 2 < nt);
    const us* gA2 = gA + (size_t)(t + 2) * 64;
    const us* gB2 = gB + (size_t)(t + 2) * 64;
    const char* pa = (const char*)buf + (size_t)(wm * 64 + r15) * 128;
    const char* pb = (const char*)buf + (size_t)(BM + wn * 64 + r15) * 128;

    if (dostage) stageR<BM, 0, 3>(nbuf, gA2, sA, gB2, sB, wave, lane);
    bf16x8 A0[4], B0[4];
#pragma unroll
    for (int f = 0; f < 4; ++f) A0[f] = *(const bf16x8*)(pa + f * 2048 + x0);
#pragma unroll
    for (int f = 0; f < 4; ++f) B0[f] = *(const bf16x8*)(pb + f * 2048 + x0);
    __builtin_amdgcn_s_setprio(1);
#pragma unroll
    for (int fn = 0; fn < 4; ++fn)
#pragma unroll
      for (int fm = 0; fm < 4; ++fm)
        acc[fm][fn] = __builtin_amdgcn_mfma_f32_16x16x32_bf16(A0[fm], B0[fn], acc[fm][fn], 0, 0, 0);
    __builtin_amdgcn_s_setprio(0);

    if (dostage) stageR<BM, 3, 6>(nbuf, gA2, sA, gB2, sB, wave, lane);
    bf16x8 A1[4], B1[4];
#pragma unroll
    for (int f = 0; f < 4; ++f) A1[f] = *(const bf16x8*)(pa + f * 2048 + (x0 ^ 64));
#pragma unroll
    for (int f = 0; f < 4; ++f) B1[f] = *(const bf16x8*)(pb + f * 2048 + (x0 ^ 64));
    __builtin_amdgcn_s_setprio(1);
#pragma unroll
    for (int fn = 0; fn < 4; ++fn)
#pragma unroll
      for (int fm = 0; fm < 4; ++fm)
        acc[fm][fn] = __builtin_amdgcn_mfma_f32_16x16x32_bf16(A1[fm], B1[fn], acc[fm][fn], 0, 0, 0);
    __builtin_amdgcn_s_setprio(0);
  }

#pragma unroll
  for (int fm = 0; fm < 4; ++fm)
#pragma unroll
    for (int fn = 0; fn < 4; ++fn) {
      int col = n0 + wn * 64 + fn * 16 + r15;
      int row0 = m0 + wm * 64 + fm * 16 + ((lane >> 4) << 2);
      if constexpr (EPI == 0) {
        int mat = col >> 10;
        const float* bp = (mat == 0) ? bq : (mat == 1) ? bk : bv;
        float bb = bp[col & 1023];
        if (mat < 2) {
          us* ob = (us*)outp + ((size_t)mat << 23);
#pragma unroll
          for (int r = 0; r < 4; ++r)
            ob[(size_t)(row0 + r) * D_ + (col & 1023)] = f2bf(acc[fm][fn][r] + bb);
        } else {
          // v written transposed: vtb[b][d][t]  (verified R7/R8)
          int b = row0 >> 11, trow = row0 & 2047, dcol = col & 1023;
          us4 v4 = {f2bf(acc[fm][fn][0] + bb), f2bf(acc[fm][fn][1] + bb),
                    f2bf(acc[fm][fn][2] + bb), f2bf(acc[fm][fn][3] + bb)};
          *(us4*)(vtb + (size_t)b * D_ * S_ + (size_t)dcol * S_ + trow) = v4;
        }
      } else {
        float* ob = (float*)outp + bz * (size_t)(S_ * D_);
#pragma unroll
        for (int r = 0; r < 4; ++r)
          ob[(size_t)(row0 + r) * D_ + col] = acc[fm][fn][r];
      }
    }
}

// ==================== gemm256k (R8, 0-conflict swizzle) for s2 ====================
// 256x256, BK=32, 8 waves (2x4), 3x32KiB. Grid must be an exact 256 multiple.
__global__ __launch_bounds__(512, 2) void s2k(
    const us* __restrict__ Aall, const us* __restrict__ Ball,
    _Float16* __restrict__ scores) {
  __shared__ __align__(16) us lds3[3][16384];
  const int tid = threadIdx.x, lane = tid & 63, wave = tid >> 6;
  const int wm = wave >> 2, wn = wave & 3;      // wave-tile 128x64
  const int m0 = blockIdx.x * 256, n0 = blockIdx.y * 256;
  const size_t bz = blockIdx.z;
  const char* gA = (const char*)(Aall + bz * (size_t)(S_ * D_) + (size_t)m0 * D_);
  const char* gB = (const char*)(Ball + bz * (size_t)(S_ * D_) + (size_t)n0 * D_);
  const size_t sA = (size_t)D_ * 2, sB = (size_t)D_ * 2;
  const int nt = 32;

  const int r15 = lane & 15, kg = lane >> 4;
  const int srcslot = (((lane & 3) ^ ((lane >> 3) & 3)) << 4);
  const int srow = wave * 16 + (lane >> 2);

  auto stage = [&](int bi, int t) {
    char* l = (char*)lds3[bi];
    const size_t koff = (size_t)t * 64;
#pragma unroll
    for (int r = 0; r < 4; ++r) {
      int row = r * 128 + srow;
      const char* src = (row < 256)
          ? gA + (size_t)row * sA + koff + srcslot
          : gB + (size_t)(row - 256) * sB + koff + srcslot;
      gl2lds16(l + r * 8192 + wave * 1024, src);
    }
  };

  stage(0, 0);
  stage(1, 1);

  f32x4 acc[8][4] = {};
  for (int t = 0; t < nt; ++t) {
    if (t == nt - 1) asm volatile("s_waitcnt vmcnt(0)" ::: "memory");
    else             asm volatile("s_waitcnt vmcnt(4)" ::: "memory");
    barrier_f();
    if (t + 2 < nt) stage((t + 2) % 3, t + 2);
    const char* buf = (const char*)lds3[t % 3];

    bf16x8 Af[8], Bf[4];
#pragma unroll
    for (int f = 0; f < 8; ++f) {
      int tr = wm * 128 + f * 16 + r15;
      Af[f] = *(const bf16x8*)(buf + tr * 64 + ((kg ^ ((tr >> 1) & 3)) << 4));
    }
#pragma unroll
    for (int n = 0; n < 4; ++n) {
      int tr = 256 + wn * 64 + n * 16 + r15;
      Bf[n] = *(const bf16x8*)(buf + tr * 64 + ((kg ^ ((tr >> 1) & 3)) << 4));
    }
    __builtin_amdgcn_s_setprio(1);
#pragma unroll
    for (int n = 0; n < 4; ++n)
#pragma unroll
      for (int f = 0; f < 8; ++f)
        acc[f][n] = __builtin_amdgcn_mfma_f32_16x16x32_bf16(Af[f], Bf[n], acc[f][n], 0, 0, 0);
    __builtin_amdgcn_s_setprio(0);
  }

  _Float16* sc = scores + bz * (size_t)(S_ * S_);
#pragma unroll
  for (int fm = 0; fm < 8; ++fm)
#pragma unroll
    for (int fn = 0; fn < 4; ++fn) {
      int col = n0 + wn * 64 + fn * 16 + r15;
      int row0 = m0 + wm * 128 + fm * 16 + ((lane >> 4) << 2);
#pragma unroll
      for (int r = 0; r < 4; ++r)
        sc[(size_t)(row0 + r) * S_ + col] = (_Float16)(acc[fm][fn][r] * 0.03125f);
    }
}

// ---------------- W [k][n] fp32 -> Wt bf16 [n][k] (n = mat*1024 + col) ----------------
__global__ __launch_bounds__(256) void wt_prep(const float* __restrict__ Wq,
                                               const float* __restrict__ Wk,
                                               const float* __restrict__ Wv,
                                               us* __restrict__ wtb) {
  __shared__ us hs[64][65];
  int mat = blockIdx.z;
  const float* W = (mat == 0) ? Wq : (mat == 1) ? Wk : Wv;
  int n0 = blockIdx.x * 64, k0 = blockIdx.y * 64;
  int tid = threadIdx.x;
#pragma unroll
  for (int i = 0; i < 16; ++i) {
    int idx = tid + i * 256;
    int r = idx >> 6, c = idx & 63;
    hs[r][c] = f2bf(W[(size_t)(k0 + r) * D_ + (n0 + c)]);
  }
  __syncthreads();
  us* o = wtb + ((size_t)mat << 20);
#pragma unroll
  for (int i = 0; i < 16; ++i) {
    int idx = tid + i * 256;
    int r = idx >> 6, c = idx & 63;
    o[(size_t)(n0 + r) * D_ + (k0 + c)] = hs[c][r];
  }
}

// ---------------- x fp32 -> xb bf16 ----------------
__global__ __launch_bounds__(256) void xcast(const float* __restrict__ x,
                                             us* __restrict__ xb) {
  size_t i = ((size_t)blockIdx.x * 256 + threadIdx.x) * 8;
  float4 f0 = *(const float4*)(x + i);
  float4 f1 = *(const float4*)(x + i + 4);
  float vals[8] = {f0.x, f0.y, f0.z, f0.w, f1.x, f1.y, f1.z, f1.w};
  union { bf16x8 v; us s_[8]; } H;
#pragma unroll
  for (int e = 0; e < 8; ++e) H.s_[e] = f2bf(vals[e]);
  *(bf16x8*)(xb + i) = H.v;
}

// ---------------- row softmax: fp16 scores -> P bf16 (h8 vectorized) ----------------
__global__ __launch_bounds__(256) void softmax_k(const _Float16* __restrict__ scores,
                                                 us* __restrict__ pb) {
  int row = blockIdx.x, tid = threadIdx.x, lane = tid & 63, wave = tid >> 6;
  const _Float16* s = scores + (size_t)row * S_;
  h8v a8 = *(const h8v*)(s + tid * 8);
  float a[8];
#pragma unroll
  for (int e = 0; e < 8; ++e) a[e] = (float)a8[e];
  float m = a[0];
#pragma unroll
  for (int e = 1; e < 8; ++e) m = fmaxf(m, a[e]);
#pragma unroll
  for (int o = 32; o; o >>= 1) m = fmaxf(m, __shfl_xor(m, o));
  __shared__ float red[4];
  if (lane == 0) red[wave] = m;
  __syncthreads();
  m = fmaxf(fmaxf(red[0], red[1]), fmaxf(red[2], red[3]));
  float p[8];
  float sum = 0.f;
#pragma unroll
  for (int e = 0; e < 8; ++e) { p[e] = expf(a[e] - m); sum += p[e]; }
#pragma unroll
  for (int o = 32; o; o >>= 1) sum += __shfl_xor(sum, o);
  __syncthreads();
  if (lane == 0) red[wave] = sum;
  __syncthreads();
  float inv = 1.0f / (red[0] + red[1] + red[2] + red[3]);
  us8 h;
#pragma unroll
  for (int e = 0; e < 8; ++e) h[e] = f2bf(p[e] * inv);
  *(us8*)(pb + (size_t)row * S_ + tid * 8) = h;
}

extern "C" void kernel_launch(void* const* d_in, const int* in_sizes, int n_in,
                              void* d_out, int out_size, void* d_ws, size_t ws_size,
                              hipStream_t stream) {
  const float* x  = (const float*)d_in[0];
  const float* Wq = (const float*)d_in[1];
  const float* bq = (const float*)d_in[2];
  const float* Wk = (const float*)d_in[3];
  const float* bk = (const float*)d_in[4];
  const float* Wv = (const float*)d_in[5];
  const float* bv = (const float*)d_in[6];
  float* out = (float*)d_out;
  char* ws = (char*)d_ws;
  const size_t MB = 1024 * 1024;
  // Layout (118 MiB): qb [0,16) kb [16,32) vtb [32,48) wtb [48,54)
  //                   xb [54,70) scores [70,102) pb [102,118)
  us* qb   = (us*)(ws + 0 * MB);
  us* kb   = (us*)(ws + 16 * MB);
  us* vtb  = (us*)(ws + 32 * MB);
  us* wtb  = (us*)(ws + 48 * MB);
  us* xb   = (us*)(ws + 54 * MB);
  _Float16* scores = (_Float16*)(ws + 70 * MB);
  us* pb   = (us*)(ws + 102 * MB);

  wt_prep<<<dim3(16, 16, 3), 256, 0, stream>>>(Wq, Wk, Wv, wtb);
  xcast<<<dim3(4096), 256, 0, stream>>>(x, xb);
  // qkv: M=8192 x N=3072 x K=1024 -> grid 768 = 3 exact rounds (R5-proven)
  gemm8p<0, 128, 256, 4><<<dim3(64, 12, 1), 512, 0, stream>>>(
      xb, wtb, 0, 0, D_, D_, 16, bq, bk, bv, qb, vtb);
  // s2: per batch 2048 x 2048 x 1024 -> grid 256 = 1 exact round
  s2k<<<dim3(8, 8, 4), 512, 0, stream>>>(qb, kb, scores);
  softmax_k<<<dim3(B_ * S_), 256, 0, stream>>>(scores, pb);
  // s3: per batch 2048 x 1024 x 2048 -> grid 256 = 1 exact round
  gemm8p<2, 256, 128, 2><<<dim3(8, 8, 4), 512, 0, stream>>>(
      pb, vtb, (size_t)S_ * S_, (size_t)D_ * S_, S_, S_, 32,
      nullptr, nullptr, nullptr, out, nullptr);
}